// Round 14
// baseline (781.119 us; speedup 1.0000x reference)
//
#include <hip/hip_runtime.h>
#include <hip/hip_bf16.h>
#include <stdint.h>

#define M_TOK 4096
#define DDIM  2048
#define HDIM  2816
#define NEXP  8
#define PMAX  10240     // 40 * 256 >= 8192 + 8*255
#define MAXTILES 40
#define CVW   8         // extra grid.x rows in gemm1 for w2 conversion
#define NB1   44        // HDIM / 64 col blocks (gemm1: 64 gate + 64 up each)
#define NB2   16        // DDIM / 128 col blocks (gemm2)
#define NKT1  32        // DDIM / 64
#define NKT2  44        // HDIM / 64
#define W2CHUNK 32768   // float4 per w2-cvt chunk: 8*2048*2816/4 / (CVW*NB1) = 32768

typedef __attribute__((ext_vector_type(8))) short short8;
typedef __attribute__((ext_vector_type(4))) float f32x4;

#define GLD16(g, l) __builtin_amdgcn_global_load_lds(                              \
    (const __attribute__((address_space(1))) unsigned int*)(g),                    \
    (__attribute__((address_space(3))) unsigned int*)(l), 16, 0, 0)

#define VMCNT(n) asm volatile("s_waitcnt vmcnt(" #n ")" ::: "memory")

__device__ __forceinline__ unsigned short f2bf(float f) {
  unsigned int u = __float_as_uint(f);
  u += 0x7fffu + ((u >> 16) & 1u);
  return (unsigned short)(u >> 16);
}
__device__ __forceinline__ float bf2f(unsigned short u) {
  return __uint_as_float(((unsigned)u) << 16);
}

// ---------------- cvt w1 fp32->bf16 + init (tok/counts/cursors, out=bias) ----------------
__global__ void cvt1_k(const float4* __restrict__ in, ushort4* __restrict__ out, int n4,
                       int* __restrict__ tok, int* __restrict__ counts,
                       int* __restrict__ cursors,
                       float4* __restrict__ outy, const float4* __restrict__ bias4) {
  int gid = blockIdx.x * blockDim.x + threadIdx.x;
  if (gid < PMAX) tok[gid] = -1;
  if (gid < NEXP) { counts[gid] = 0; cursors[gid] = 0; }
  int stride = gridDim.x * blockDim.x;
  for (int i = gid; i < M_TOK * (DDIM / 4); i += stride)
    outy[i] = bias4[i & (DDIM / 4 - 1)];
  for (int i = gid; i < n4; i += stride) {
    float4 v = in[i];
    ushort4 o;
    o.x = f2bf(v.x); o.y = f2bf(v.y); o.z = f2bf(v.z); o.w = f2bf(v.w);
    out[i] = o;
  }
}

// ---------------- router (fused x->bf16 conversion; R13 verbatim) ----------------
__global__ __launch_bounds__(256) void router_k(const float4* __restrict__ x4,
                                                const float4* __restrict__ rw4,
                                                ushort4* __restrict__ xb4,
                                                float* __restrict__ wgt,
                                                int* __restrict__ eid,
                                                int* __restrict__ counts) {
  int lane = threadIdx.x & 63;
  int wv = threadIdx.x >> 6;
  int t = blockIdx.x * 4 + wv;
  int base = t * (DDIM / 4);
  float acc[NEXP];
#pragma unroll
  for (int e = 0; e < NEXP; ++e) acc[e] = 0.f;
#pragma unroll
  for (int j = 0; j < DDIM / 4 / 64; ++j) {
    float4 v = x4[base + j * 64 + lane];
    ushort4 o;
    o.x = f2bf(v.x); o.y = f2bf(v.y); o.z = f2bf(v.z); o.w = f2bf(v.w);
    xb4[base + j * 64 + lane] = o;
#pragma unroll
    for (int e = 0; e < NEXP; ++e) {
      float4 w = rw4[e * (DDIM / 4) + j * 64 + lane];
      acc[e] += v.x * w.x + v.y * w.y + v.z * w.z + v.w * w.w;
    }
  }
#pragma unroll
  for (int e = 0; e < NEXP; ++e) {
#pragma unroll
    for (int s = 32; s > 0; s >>= 1) acc[e] += __shfl_xor(acc[e], s, 64);
  }
  if (lane == 0) {
    float mx = acc[0];
#pragma unroll
    for (int e = 1; e < NEXP; ++e) mx = fmaxf(mx, acc[e]);
    float p[NEXP];
#pragma unroll
    for (int e = 0; e < NEXP; ++e) p[e] = expf(acc[e] - mx);
    int e0 = 0; float p0 = p[0];
#pragma unroll
    for (int e = 1; e < NEXP; ++e) if (p[e] > p0) { p0 = p[e]; e0 = e; }
    int e1 = -1; float p1 = -1.f;
#pragma unroll
    for (int e = 0; e < NEXP; ++e) if (e != e0 && p[e] > p1) { p1 = p[e]; e1 = e; }
    float s = p0 + p1;
    wgt[2 * t] = p0 / s; wgt[2 * t + 1] = p1 / s;
    eid[2 * t] = e0;     eid[2 * t + 1] = e1;
    atomicAdd(&counts[e0], 1);
    atomicAdd(&counts[e1], 1);
  }
}

// ---------------- offsets + tile map + scatter (+ per-slot weight) ----------------
__global__ __launch_bounds__(256) void offscat_k(const int* __restrict__ counts,
                                                 int* __restrict__ tile2exp,
                                                 int* __restrict__ tilerow,
                                                 int* __restrict__ ntiles,
                                                 const int* __restrict__ eid,
                                                 const float* __restrict__ wgt,
                                                 int* __restrict__ cursors,
                                                 int* __restrict__ tok,
                                                 float* __restrict__ wslot) {
  __shared__ int soffs[NEXP];
  if (threadIdx.x == 0) {
    int o = 0, nt = 0;
    for (int e = 0; e < NEXP; ++e) {
      soffs[e] = o;
      int c = counts[e];
      int pt = (c + 255) >> 8;
      for (int i = 0; i < pt; ++i) { tile2exp[nt] = e; tilerow[nt] = o + i * 256; ++nt; }
      o += pt << 8;
    }
    ntiles[0] = nt;
  }
  __syncthreads();
  for (int t = threadIdx.x; t < M_TOK; t += 256) {
#pragma unroll
    for (int k = 0; k < 2; ++k) {
      int e = eid[2 * t + k];
      int p = soffs[e] + atomicAdd(&cursors[e], 1);
      tok[p] = t;
      wslot[p] = wgt[2 * t + k];
    }
  }
}

// =============== GEMM1 (R13 core) + interleaved w2 fp32->bf16 blocks ===============
__global__ __launch_bounds__(256, 2) void gemm1_k(const unsigned short* __restrict__ xb,
                                                  const unsigned short* __restrict__ w1b,
                                                  const int* __restrict__ tok,
                                                  const int* __restrict__ tile2exp,
                                                  const int* __restrict__ tilerow,
                                                  const int* __restrict__ ntiles,
                                                  unsigned short* __restrict__ h,
                                                  const float4* __restrict__ w2src,
                                                  ushort4* __restrict__ w2dst) {
  __shared__ char ldsp[65536];
  int bx = blockIdx.x;
  if (bx >= MAXTILES) {
    // fused w2 conversion: 256-thr block co-resident with a gemm block (2/CU)
    int chunk = (bx - MAXTILES) * NB1 + blockIdx.y;   // 0..351
    int base = chunk * W2CHUNK;
    for (int i = base + threadIdx.x; i < base + W2CHUNK; i += 256) {
      float4 v = w2src[i];
      ushort4 o;
      o.x = f2bf(v.x); o.y = f2bf(v.y); o.z = f2bf(v.z); o.w = f2bf(v.w);
      w2dst[i] = o;
    }
    return;
  }
  int mt = bx;
  if (mt >= ntiles[0]) return;
  int e = tile2exp[mt], r0 = tilerow[mt];
  int n0 = blockIdx.y * 64;
  int tid = threadIdx.x, lane = tid & 63;
  int wv = tid >> 6, wm = wv >> 1, wn = wv & 1;
  int l15 = lane & 15, lq = lane >> 4;

  int sg = tid & 7, srow = tid >> 3;   // srow 0..31
  unsigned int aOff[8], bOff[4];
#pragma unroll
  for (int j = 0; j < 8; ++j) {
    int r = j * 32 + srow;
    int t = tok[r0 + r]; if (t < 0) t = 0;
    aOff[j] = (unsigned int)t * (DDIM * 2) + (unsigned int)((sg ^ (r & 7)) << 4);
  }
#pragma unroll
  for (int j = 0; j < 4; ++j) {
    int r = j * 32 + srow;           // 0..63 gate cols, 64..127 up cols
    int w1row = e * (2 * HDIM) + (r < 64 ? n0 + r : HDIM + n0 + (r - 64));
    bOff[j] = (unsigned int)w1row * (DDIM * 2) + (unsigned int)((sg ^ (r & 7)) << 4);
  }

  int aRd[8], bRd[4];
#pragma unroll
  for (int i = 0; i < 8; ++i) {
    int r = wm * 128 + i * 16 + l15;
    aRd[i] = r * 128 + ((lq ^ (r & 7)) << 4);
  }
#pragma unroll
  for (int i = 0; i < 4; ++i) {
    int r = wn * 64 + i * 16 + l15;
    bRd[i] = r * 128 + ((lq ^ (r & 7)) << 4);
  }

  f32x4 acc[8][4];
#pragma unroll
  for (int mi = 0; mi < 8; ++mi)
#pragma unroll
    for (int ni = 0; ni < 4; ++ni) acc[mi][ni] = (f32x4)(0.f);

  const char* xB = (const char*)xb;
  const char* wB = (const char*)w1b;

#pragma unroll 1
  for (int kt = 0; kt < NKT1; ++kt) {
    __syncthreads();
    unsigned int kb = (unsigned int)kt * 128;
#pragma unroll
    for (int j = 0; j < 8; ++j) GLD16(xB + aOff[j] + kb, ldsp + j * 4096 + tid * 16);
#pragma unroll
    for (int j = 0; j < 4; ++j) GLD16(wB + bOff[j] + kb, ldsp + 32768 + j * 4096 + tid * 16);
    VMCNT(0);
    __syncthreads();
#pragma unroll
    for (int kh = 0; kh < 2; ++kh) {
      int kx = kh << 6;
      short8 a[8], b[4];
#pragma unroll
      for (int i = 0; i < 8; ++i) a[i] = *(const short8*)(ldsp + (aRd[i] ^ kx));
#pragma unroll
      for (int i = 0; i < 4; ++i) b[i] = *(const short8*)(ldsp + 32768 + (bRd[i] ^ kx));
      __builtin_amdgcn_s_setprio(1);
#pragma unroll
      for (int mi = 0; mi < 8; ++mi)
#pragma unroll
        for (int ni = 0; ni < 4; ++ni)
          acc[mi][ni] = __builtin_amdgcn_mfma_f32_16x16x32_bf16(a[mi], b[ni], acc[mi][ni], 0, 0, 0);
      __builtin_amdgcn_s_setprio(0);
    }
  }

  // GLU epilogue: up wave -> LDS f32 [256][64] (lq-XOR swizzle), gate wave reads
  __syncthreads();
  float* xch = (float*)ldsp;
  if (wn == 1) {
#pragma unroll
    for (int mi = 0; mi < 8; ++mi)
#pragma unroll
      for (int ni = 0; ni < 4; ++ni)
#pragma unroll
        for (int j = 0; j < 4; ++j) {
          int r = wm * 128 + mi * 16 + lq * 4 + j;
          int c = ni * 16 + l15;
          xch[r * 64 + (c ^ (lq << 2))] = acc[mi][ni][j];
        }
  }
  __syncthreads();
  if (wn == 0) {
#pragma unroll
    for (int mi = 0; mi < 8; ++mi)
#pragma unroll
      for (int ni = 0; ni < 4; ++ni)
#pragma unroll
        for (int j = 0; j < 4; ++j) {
          int r = wm * 128 + mi * 16 + lq * 4 + j;
          int c = ni * 16 + l15;
          float u = xch[r * 64 + (c ^ (lq << 2))];
          float gg = acc[mi][ni][j];
          float sv = gg / (1.f + expf(-gg));
          h[(size_t)(r0 + r) * HDIM + n0 + c] = f2bf(sv * u);
        }
  }
}

// =============== GEMM2 (R13 core) + fused weighted atomic combine ===============
__global__ __launch_bounds__(256, 2) void gemm2_k(const unsigned short* __restrict__ h,
                                                  const unsigned short* __restrict__ w2b,
                                                  const int* __restrict__ tile2exp,
                                                  const int* __restrict__ tilerow,
                                                  const int* __restrict__ ntiles,
                                                  const int* __restrict__ tok,
                                                  const float* __restrict__ wslot,
                                                  float* __restrict__ out) {
  __shared__ char ldsp[49152];
  int mt = blockIdx.x;
  if (mt >= ntiles[0]) return;
  int e = tile2exp[mt], r0 = tilerow[mt];
  int n0 = blockIdx.y * 128;
  int tid = threadIdx.x, lane = tid & 63;
  int wv = tid >> 6, wm = wv >> 1, wn = wv & 1;
  int l15 = lane & 15, lq = lane >> 4;

  int sg = tid & 7, srow = tid >> 3;
  unsigned int aOff[8], bOff[4];
#pragma unroll
  for (int j = 0; j < 8; ++j) {
    int r = j * 32 + srow;
    aOff[j] = (unsigned int)(r0 + r) * (HDIM * 2) + (unsigned int)((sg ^ (r & 7)) << 4);
  }
#pragma unroll
  for (int j = 0; j < 4; ++j) {
    int r = j * 32 + srow;
    bOff[j] = (unsigned int)(e * DDIM + n0 + r) * (HDIM * 2) + (unsigned int)((sg ^ (r & 7)) << 4);
  }

  int aRd[8], bRd[4];
#pragma unroll
  for (int i = 0; i < 8; ++i) {
    int r = wm * 128 + i * 16 + l15;
    aRd[i] = r * 128 + ((lq ^ (r & 7)) << 4);
  }
#pragma unroll
  for (int i = 0; i < 4; ++i) {
    int r = wn * 64 + i * 16 + l15;
    bRd[i] = r * 128 + ((lq ^ (r & 7)) << 4);
  }

  f32x4 acc[8][4];
#pragma unroll
  for (int mi = 0; mi < 8; ++mi)
#pragma unroll
    for (int ni = 0; ni < 4; ++ni) acc[mi][ni] = (f32x4)(0.f);

  const char* hB = (const char*)h;
  const char* wB = (const char*)w2b;

#pragma unroll 1
  for (int kt = 0; kt < NKT2; ++kt) {
    __syncthreads();
    unsigned int kb = (unsigned int)kt * 128;
#pragma unroll
    for (int j = 0; j < 8; ++j) GLD16(hB + aOff[j] + kb, ldsp + j * 4096 + tid * 16);
#pragma unroll
    for (int j = 0; j < 4; ++j) GLD16(wB + bOff[j] + kb, ldsp + 32768 + j * 4096 + tid * 16);
    VMCNT(0);
    __syncthreads();
#pragma unroll
    for (int kh = 0; kh < 2; ++kh) {
      int kx = kh << 6;
      short8 a[8], b[4];
#pragma unroll
      for (int i = 0; i < 8; ++i) a[i] = *(const short8*)(ldsp + (aRd[i] ^ kx));
#pragma unroll
      for (int i = 0; i < 4; ++i) b[i] = *(const short8*)(ldsp + 32768 + (bRd[i] ^ kx));
      __builtin_amdgcn_s_setprio(1);
#pragma unroll
      for (int mi = 0; mi < 8; ++mi)
#pragma unroll
        for (int ni = 0; ni < 4; ++ni)
          acc[mi][ni] = __builtin_amdgcn_mfma_f32_16x16x32_bf16(a[mi], b[ni], acc[mi][ni], 0, 0, 0);
      __builtin_amdgcn_s_setprio(0);
    }
  }

  // fused combine: out[t] += wslot[p] * acc  (pad rows tok<0 skipped;
  // out pre-initialized to bias; each out element receives exactly 2 adds)
#pragma unroll
  for (int mi = 0; mi < 8; ++mi)
#pragma unroll
    for (int j = 0; j < 4; ++j) {
      int p = r0 + wm * 128 + mi * 16 + lq * 4 + j;
      int t = tok[p];
      if (t < 0) continue;
      float w = wslot[p];
      float* orow = out + (size_t)t * DDIM + n0 + wn * 64;
#pragma unroll
      for (int ni = 0; ni < 4; ++ni)
        atomicAdd(orow + ni * 16 + l15, w * acc[mi][ni][j]);
    }
}

extern "C" void kernel_launch(void* const* d_in, const int* in_sizes, int n_in,
                              void* d_out, int out_size, void* d_ws, size_t ws_size,
                              hipStream_t stream) {
  const float* x    = (const float*)d_in[0];
  const float* w1   = (const float*)d_in[1];
  const float* w2   = (const float*)d_in[2];
  const float* rw   = (const float*)d_in[3];
  const float* bias = (const float*)d_in[4];
  float* out = (float*)d_out;

  char* ws = (char*)d_ws;
  size_t off = 0;
  auto alloc = [&](size_t bytes) -> void* {
    void* p = ws + off;
    off = (off + bytes + 255) & ~(size_t)255;
    return p;
  };
  unsigned short* w1b = (unsigned short*)alloc((size_t)NEXP * 2 * HDIM * DDIM * 2);
  unsigned short* w2b = (unsigned short*)alloc((size_t)NEXP * DDIM * HDIM * 2);
  unsigned short* xb  = (unsigned short*)alloc((size_t)M_TOK * DDIM * 2);
  unsigned short* h   = (unsigned short*)alloc((size_t)PMAX * HDIM * 2);
  float* wgt          = (float*)alloc((size_t)M_TOK * 2 * 4);
  int* eid            = (int*)alloc((size_t)M_TOK * 2 * 4);
  int* tok            = (int*)alloc((size_t)PMAX * 4);
  float* wslot        = (float*)alloc((size_t)PMAX * 4);
  int* counts         = (int*)alloc(64 * 4);
  int* cursors        = (int*)alloc(64 * 4);
  int* ntiles         = (int*)alloc(64 * 4);
  int* tile2exp       = (int*)alloc(128 * 4);
  int* tilerow        = (int*)alloc(128 * 4);

  const int n1 = (int)((size_t)NEXP * 2 * HDIM * DDIM / 4);
  hipLaunchKernelGGL(cvt1_k, dim3(2048), dim3(256), 0, stream,
                     (const float4*)w1, (ushort4*)w1b, n1, tok, counts, cursors,
                     (float4*)out, (const float4*)bias);
  hipLaunchKernelGGL(router_k, dim3(M_TOK / 4), dim3(256), 0, stream,
                     (const float4*)x, (const float4*)rw, (ushort4*)xb, wgt, eid, counts);
  hipLaunchKernelGGL(offscat_k, dim3(1), dim3(256), 0, stream,
                     counts, tile2exp, tilerow, ntiles, eid, wgt, cursors, tok, wslot);
  hipLaunchKernelGGL(gemm1_k, dim3(MAXTILES + CVW, NB1), dim3(256), 0, stream,
                     xb, w1b, tok, tile2exp, tilerow, ntiles, h,
                     (const float4*)w2, (ushort4*)w2b);
  hipLaunchKernelGGL(gemm2_k, dim3(MAXTILES, NB2), dim3(256), 0, stream,
                     h, w2b, tile2exp, tilerow, ntiles, tok, wslot, out);
}

// Round 15
// 773.998 us; speedup vs baseline: 1.0092x; 1.0092x over previous
//
#include <hip/hip_runtime.h>
#include <hip/hip_bf16.h>
#include <stdint.h>

#define M_TOK 4096
#define DDIM  2048
#define HDIM  2816
#define NEXP  8
#define PMAX  10240     // 40 * 256 >= 8192 + 8*255
#define MAXTILES 40
#define NB1   44        // HDIM / 64 col blocks (gemm1: 64 gate + 64 up each)
#define NB2   16        // DDIM / 128 col blocks (gemm2)
#define NKT1  32        // DDIM / 64
#define NKT2  44        // HDIM / 64
#define NWG1  (MAXTILES * NB1)   // 1760, %8 == 0
#define NWG2  (MAXTILES * NB2)   // 640,  %8 == 0

typedef __attribute__((ext_vector_type(8))) short short8;
typedef __attribute__((ext_vector_type(4))) float f32x4;

#define GLD16(g, l) __builtin_amdgcn_global_load_lds(                              \
    (const __attribute__((address_space(1))) unsigned int*)(g),                    \
    (__attribute__((address_space(3))) unsigned int*)(l), 16, 0, 0)

#define VMCNT(n) asm volatile("s_waitcnt vmcnt(" #n ")" ::: "memory")

__device__ __forceinline__ unsigned short f2bf(float f) {
  unsigned int u = __float_as_uint(f);
  u += 0x7fffu + ((u >> 16) & 1u);
  return (unsigned short)(u >> 16);
}
__device__ __forceinline__ float bf2f(unsigned short u) {
  return __uint_as_float(((unsigned)u) << 16);
}

// ---------------- mega: router (blocks 0..1023) + cvt w1 (1024..3071)
//                  + cvt w2 & tok-init (3072..4095), one launch ----------------
__global__ __launch_bounds__(256) void mega_k(const float4* __restrict__ x4,
                                              const float4* __restrict__ rw4,
                                              ushort4* __restrict__ xb4,
                                              float* __restrict__ wgt,
                                              int* __restrict__ eid,
                                              int* __restrict__ counts,
                                              const float4* __restrict__ w14,
                                              ushort4* __restrict__ w1b4, int n1,
                                              const float4* __restrict__ w24,
                                              ushort4* __restrict__ w2b4, int n2,
                                              int* __restrict__ tok) {
  int b = blockIdx.x;
  if (b < 1024) {
    // ---- router block (R13 logic) ----
    int lane = threadIdx.x & 63;
    int wv = threadIdx.x >> 6;
    int t = b * 4 + wv;
    int base = t * (DDIM / 4);
    float acc[NEXP];
#pragma unroll
    for (int e = 0; e < NEXP; ++e) acc[e] = 0.f;
#pragma unroll
    for (int j = 0; j < DDIM / 4 / 64; ++j) {
      float4 v = x4[base + j * 64 + lane];
      ushort4 o;
      o.x = f2bf(v.x); o.y = f2bf(v.y); o.z = f2bf(v.z); o.w = f2bf(v.w);
      xb4[base + j * 64 + lane] = o;
#pragma unroll
      for (int e = 0; e < NEXP; ++e) {
        float4 w = rw4[e * (DDIM / 4) + j * 64 + lane];
        acc[e] += v.x * w.x + v.y * w.y + v.z * w.z + v.w * w.w;
      }
    }
#pragma unroll
    for (int e = 0; e < NEXP; ++e) {
#pragma unroll
      for (int s = 32; s > 0; s >>= 1) acc[e] += __shfl_xor(acc[e], s, 64);
    }
    if (lane == 0) {
      float mx = acc[0];
#pragma unroll
      for (int e = 1; e < NEXP; ++e) mx = fmaxf(mx, acc[e]);
      float p[NEXP];
#pragma unroll
      for (int e = 0; e < NEXP; ++e) p[e] = expf(acc[e] - mx);
      int e0 = 0; float p0 = p[0];
#pragma unroll
      for (int e = 1; e < NEXP; ++e) if (p[e] > p0) { p0 = p[e]; e0 = e; }
      int e1 = -1; float p1 = -1.f;
#pragma unroll
      for (int e = 0; e < NEXP; ++e) if (e != e0 && p[e] > p1) { p1 = p[e]; e1 = e; }
      float s = p0 + p1;
      wgt[2 * t] = p0 / s; wgt[2 * t + 1] = p1 / s;
      eid[2 * t] = e0;     eid[2 * t + 1] = e1;
      atomicAdd(&counts[e0], 1);
      atomicAdd(&counts[e1], 1);
    }
  } else if (b < 3072) {
    // ---- w1 fp32 -> bf16 ----
    int id = b - 1024;
    const int stride = 2048 * 256;
    for (int i = id * 256 + threadIdx.x; i < n1; i += stride) {
      float4 v = w14[i];
      ushort4 o;
      o.x = f2bf(v.x); o.y = f2bf(v.y); o.z = f2bf(v.z); o.w = f2bf(v.w);
      w1b4[i] = o;
    }
  } else {
    // ---- w2 fp32 -> bf16 + tok init ----
    int id = b - 3072;
    int gid = id * 256 + threadIdx.x;
    if (gid < PMAX) tok[gid] = -1;
    const int stride = 1024 * 256;
    for (int i = gid; i < n2; i += stride) {
      float4 v = w24[i];
      ushort4 o;
      o.x = f2bf(v.x); o.y = f2bf(v.y); o.z = f2bf(v.z); o.w = f2bf(v.w);
      w2b4[i] = o;
    }
  }
}

// ---------------- offsets + tile map + scatter (R13 verbatim) ----------------
__global__ __launch_bounds__(256) void offscat_k(const int* __restrict__ counts,
                                                 int* __restrict__ tile2exp,
                                                 int* __restrict__ tilerow,
                                                 int* __restrict__ ntiles,
                                                 const int* __restrict__ eid,
                                                 int* __restrict__ cursors,
                                                 int* __restrict__ tok,
                                                 int* __restrict__ slot) {
  __shared__ int soffs[NEXP];
  if (threadIdx.x == 0) {
    int o = 0, nt = 0;
    for (int e = 0; e < NEXP; ++e) {
      soffs[e] = o;
      int c = counts[e];
      int pt = (c + 255) >> 8;
      for (int i = 0; i < pt; ++i) { tile2exp[nt] = e; tilerow[nt] = o + i * 256; ++nt; }
      o += pt << 8;
    }
    ntiles[0] = nt;
  }
  __syncthreads();
  for (int t = threadIdx.x; t < M_TOK; t += 256) {
#pragma unroll
    for (int k = 0; k < 2; ++k) {
      int e = eid[2 * t + k];
      int p = soffs[e] + atomicAdd(&cursors[e], 1);
      tok[p] = t;
      slot[2 * t + k] = p;
    }
  }
}

// =============== GEMM1 (R13 core) + XCD-aware tile-major swizzle ===============
// Linear grid NWG1; wg=(id&7)*(NWG1/8)+id/8 -> XCD k owns tiles [5k,5k+5)
// x all 44 colblocks: its 5 A-panels (~5MB) pin in the XCD's 4MB L2.
__global__ __launch_bounds__(256, 2) void gemm1_k(const unsigned short* __restrict__ xb,
                                                  const unsigned short* __restrict__ w1b,
                                                  const int* __restrict__ tok,
                                                  const int* __restrict__ tile2exp,
                                                  const int* __restrict__ tilerow,
                                                  const int* __restrict__ ntiles,
                                                  unsigned short* __restrict__ h) {
  __shared__ char ldsp[65536];
  int id = blockIdx.x;
  int wg = (id & 7) * (NWG1 / 8) + (id >> 3);
  int mt = wg / NB1;
  if (mt >= ntiles[0]) return;
  int e = tile2exp[mt], r0 = tilerow[mt];
  int n0 = (wg % NB1) * 64;
  int tid = threadIdx.x, lane = tid & 63;
  int wv = tid >> 6, wm = wv >> 1, wn = wv & 1;
  int l15 = lane & 15, lq = lane >> 4;

  int sg = tid & 7, srow = tid >> 3;   // srow 0..31
  unsigned int aOff[8], bOff[4];
#pragma unroll
  for (int j = 0; j < 8; ++j) {
    int r = j * 32 + srow;
    int t = tok[r0 + r]; if (t < 0) t = 0;
    aOff[j] = (unsigned int)t * (DDIM * 2) + (unsigned int)((sg ^ (r & 7)) << 4);
  }
#pragma unroll
  for (int j = 0; j < 4; ++j) {
    int r = j * 32 + srow;           // 0..63 gate cols, 64..127 up cols
    int w1row = e * (2 * HDIM) + (r < 64 ? n0 + r : HDIM + n0 + (r - 64));
    bOff[j] = (unsigned int)w1row * (DDIM * 2) + (unsigned int)((sg ^ (r & 7)) << 4);
  }

  int aRd[8], bRd[4];
#pragma unroll
  for (int i = 0; i < 8; ++i) {
    int r = wm * 128 + i * 16 + l15;
    aRd[i] = r * 128 + ((lq ^ (r & 7)) << 4);
  }
#pragma unroll
  for (int i = 0; i < 4; ++i) {
    int r = wn * 64 + i * 16 + l15;
    bRd[i] = r * 128 + ((lq ^ (r & 7)) << 4);
  }

  f32x4 acc[8][4];
#pragma unroll
  for (int mi = 0; mi < 8; ++mi)
#pragma unroll
    for (int ni = 0; ni < 4; ++ni) acc[mi][ni] = (f32x4)(0.f);

  const char* xB = (const char*)xb;
  const char* wB = (const char*)w1b;

#pragma unroll 1
  for (int kt = 0; kt < NKT1; ++kt) {
    __syncthreads();
    unsigned int kb = (unsigned int)kt * 128;
#pragma unroll
    for (int j = 0; j < 8; ++j) GLD16(xB + aOff[j] + kb, ldsp + j * 4096 + tid * 16);
#pragma unroll
    for (int j = 0; j < 4; ++j) GLD16(wB + bOff[j] + kb, ldsp + 32768 + j * 4096 + tid * 16);
    VMCNT(0);
    __syncthreads();
#pragma unroll
    for (int kh = 0; kh < 2; ++kh) {
      int kx = kh << 6;
      short8 a[8], b[4];
#pragma unroll
      for (int i = 0; i < 8; ++i) a[i] = *(const short8*)(ldsp + (aRd[i] ^ kx));
#pragma unroll
      for (int i = 0; i < 4; ++i) b[i] = *(const short8*)(ldsp + 32768 + (bRd[i] ^ kx));
      __builtin_amdgcn_s_setprio(1);
#pragma unroll
      for (int mi = 0; mi < 8; ++mi)
#pragma unroll
        for (int ni = 0; ni < 4; ++ni)
          acc[mi][ni] = __builtin_amdgcn_mfma_f32_16x16x32_bf16(a[mi], b[ni], acc[mi][ni], 0, 0, 0);
      __builtin_amdgcn_s_setprio(0);
    }
  }

  // GLU epilogue: up wave -> LDS f32 [256][64] (lq-XOR swizzle), gate wave reads
  __syncthreads();
  float* xch = (float*)ldsp;
  if (wn == 1) {
#pragma unroll
    for (int mi = 0; mi < 8; ++mi)
#pragma unroll
      for (int ni = 0; ni < 4; ++ni)
#pragma unroll
        for (int j = 0; j < 4; ++j) {
          int r = wm * 128 + mi * 16 + lq * 4 + j;
          int c = ni * 16 + l15;
          xch[r * 64 + (c ^ (lq << 2))] = acc[mi][ni][j];
        }
  }
  __syncthreads();
  if (wn == 0) {
#pragma unroll
    for (int mi = 0; mi < 8; ++mi)
#pragma unroll
      for (int ni = 0; ni < 4; ++ni)
#pragma unroll
        for (int j = 0; j < 4; ++j) {
          int r = wm * 128 + mi * 16 + lq * 4 + j;
          int c = ni * 16 + l15;
          float u = xch[r * 64 + (c ^ (lq << 2))];
          float gg = acc[mi][ni][j];
          float sv = gg / (1.f + expf(-gg));
          h[(size_t)(r0 + r) * HDIM + n0 + c] = f2bf(sv * u);
        }
  }
}

// =============== GEMM2 (R13 core) + XCD-aware tile-major swizzle ===============
__global__ __launch_bounds__(256, 2) void gemm2_k(const unsigned short* __restrict__ h,
                                                  const unsigned short* __restrict__ w2b,
                                                  const int* __restrict__ tile2exp,
                                                  const int* __restrict__ tilerow,
                                                  const int* __restrict__ ntiles,
                                                  unsigned short* __restrict__ yp) {
  __shared__ char ldsp[49152];
  int id = blockIdx.x;
  int wg = (id & 7) * (NWG2 / 8) + (id >> 3);
  int mt = wg / NB2;
  if (mt >= ntiles[0]) return;
  int e = tile2exp[mt], r0 = tilerow[mt];
  int n0 = (wg % NB2) * 128;
  int tid = threadIdx.x, lane = tid & 63;
  int wv = tid >> 6, wm = wv >> 1, wn = wv & 1;
  int l15 = lane & 15, lq = lane >> 4;

  int sg = tid & 7, srow = tid >> 3;
  unsigned int aOff[8], bOff[4];
#pragma unroll
  for (int j = 0; j < 8; ++j) {
    int r = j * 32 + srow;
    aOff[j] = (unsigned int)(r0 + r) * (HDIM * 2) + (unsigned int)((sg ^ (r & 7)) << 4);
  }
#pragma unroll
  for (int j = 0; j < 4; ++j) {
    int r = j * 32 + srow;
    bOff[j] = (unsigned int)(e * DDIM + n0 + r) * (HDIM * 2) + (unsigned int)((sg ^ (r & 7)) << 4);
  }

  int aRd[8], bRd[4];
#pragma unroll
  for (int i = 0; i < 8; ++i) {
    int r = wm * 128 + i * 16 + l15;
    aRd[i] = r * 128 + ((lq ^ (r & 7)) << 4);
  }
#pragma unroll
  for (int i = 0; i < 4; ++i) {
    int r = wn * 64 + i * 16 + l15;
    bRd[i] = r * 128 + ((lq ^ (r & 7)) << 4);
  }

  f32x4 acc[8][4];
#pragma unroll
  for (int mi = 0; mi < 8; ++mi)
#pragma unroll
    for (int ni = 0; ni < 4; ++ni) acc[mi][ni] = (f32x4)(0.f);

  const char* hB = (const char*)h;
  const char* wB = (const char*)w2b;

#pragma unroll 1
  for (int kt = 0; kt < NKT2; ++kt) {
    __syncthreads();
    unsigned int kb = (unsigned int)kt * 128;
#pragma unroll
    for (int j = 0; j < 8; ++j) GLD16(hB + aOff[j] + kb, ldsp + j * 4096 + tid * 16);
#pragma unroll
    for (int j = 0; j < 4; ++j) GLD16(wB + bOff[j] + kb, ldsp + 32768 + j * 4096 + tid * 16);
    VMCNT(0);
    __syncthreads();
#pragma unroll
    for (int kh = 0; kh < 2; ++kh) {
      int kx = kh << 6;
      short8 a[8], b[4];
#pragma unroll
      for (int i = 0; i < 8; ++i) a[i] = *(const short8*)(ldsp + (aRd[i] ^ kx));
#pragma unroll
      for (int i = 0; i < 4; ++i) b[i] = *(const short8*)(ldsp + 32768 + (bRd[i] ^ kx));
      __builtin_amdgcn_s_setprio(1);
#pragma unroll
      for (int mi = 0; mi < 8; ++mi)
#pragma unroll
        for (int ni = 0; ni < 4; ++ni)
          acc[mi][ni] = __builtin_amdgcn_mfma_f32_16x16x32_bf16(a[mi], b[ni], acc[mi][ni], 0, 0, 0);
      __builtin_amdgcn_s_setprio(0);
    }
  }

#pragma unroll
  for (int mi = 0; mi < 8; ++mi)
#pragma unroll
    for (int ni = 0; ni < 4; ++ni)
#pragma unroll
      for (int j = 0; j < 4; ++j) {
        int r = r0 + wm * 128 + mi * 16 + lq * 4 + j;
        int c = n0 + wn * 64 + ni * 16 + l15;
        yp[(size_t)r * DDIM + c] = f2bf(acc[mi][ni][j]);
      }
}

// ---------------- combine: y = w0*yp[s0] + w1*yp[s1] + bias (R13 verbatim) ----------------
__global__ void combine_k(const unsigned short* __restrict__ yp, const float* __restrict__ wgt,
                          const int* __restrict__ slot, const float* __restrict__ bias,
                          float* __restrict__ out) {
  int idx = blockIdx.x * blockDim.x + threadIdx.x;
  int t = idx >> 8, q = (idx & 255) * 8;
  float w0 = wgt[2 * t], w1 = wgt[2 * t + 1];
  int s0 = slot[2 * t], s1 = slot[2 * t + 1];
  short8 a8 = *(const short8*)(yp + (size_t)s0 * DDIM + q);
  short8 b8 = *(const short8*)(yp + (size_t)s1 * DDIM + q);
  float* op = out + (size_t)t * DDIM + q;
#pragma unroll
  for (int k = 0; k < 8; ++k) {
    float av = bf2f((unsigned short)a8[k]);
    float bv = bf2f((unsigned short)b8[k]);
    op[k] = w0 * av + w1 * bv + bias[q + k];
  }
}

extern "C" void kernel_launch(void* const* d_in, const int* in_sizes, int n_in,
                              void* d_out, int out_size, void* d_ws, size_t ws_size,
                              hipStream_t stream) {
  const float* x    = (const float*)d_in[0];
  const float* w1   = (const float*)d_in[1];
  const float* w2   = (const float*)d_in[2];
  const float* rw   = (const float*)d_in[3];
  const float* bias = (const float*)d_in[4];
  float* out = (float*)d_out;

  char* ws = (char*)d_ws;
  size_t off = 0;
  auto alloc = [&](size_t bytes) -> void* {
    void* p = ws + off;
    off = (off + bytes + 255) & ~(size_t)255;
    return p;
  };
  unsigned short* w1b = (unsigned short*)alloc((size_t)NEXP * 2 * HDIM * DDIM * 2);
  unsigned short* w2b = (unsigned short*)alloc((size_t)NEXP * DDIM * HDIM * 2);
  unsigned short* xb  = (unsigned short*)alloc((size_t)M_TOK * DDIM * 2);
  unsigned short* h   = (unsigned short*)alloc((size_t)PMAX * HDIM * 2);
  unsigned short* yp  = (unsigned short*)alloc((size_t)PMAX * DDIM * 2);
  float* wgt          = (float*)alloc((size_t)M_TOK * 2 * 4);
  int* eid            = (int*)alloc((size_t)M_TOK * 2 * 4);
  int* slot           = (int*)alloc((size_t)M_TOK * 2 * 4);
  int* tok            = (int*)alloc((size_t)PMAX * 4);
  int* counts         = (int*)alloc(64 * 4);     // counts | cursors contiguous:
  int* cursors        = (int*)alloc(64 * 4);     // one 512B memset covers both
  int* ntiles         = (int*)alloc(64 * 4);
  int* tile2exp       = (int*)alloc(128 * 4);
  int* tilerow        = (int*)alloc(128 * 4);

  const int n1 = (int)((size_t)NEXP * 2 * HDIM * DDIM / 4);
  const int n2 = (int)((size_t)NEXP * DDIM * HDIM / 4);

  hipMemsetAsync(counts, 0, 512, stream);
  hipLaunchKernelGGL(mega_k, dim3(4096), dim3(256), 0, stream,
                     (const float4*)x, (const float4*)rw, (ushort4*)xb, wgt, eid, counts,
                     (const float4*)w1, (ushort4*)w1b, n1,
                     (const float4*)w2, (ushort4*)w2b, n2, tok);
  hipLaunchKernelGGL(offscat_k, dim3(1), dim3(256), 0, stream,
                     counts, tile2exp, tilerow, ntiles, eid, cursors, tok, slot);
  hipLaunchKernelGGL(gemm1_k, dim3(NWG1), dim3(256), 0, stream,
                     xb, w1b, tok, tile2exp, tilerow, ntiles, h);
  hipLaunchKernelGGL(gemm2_k, dim3(NWG2), dim3(256), 0, stream,
                     h, w2b, tile2exp, tilerow, ntiles, yp);
  hipLaunchKernelGGL(combine_k, dim3(M_TOK * (DDIM / 8) / 256), dim3(256), 0, stream, yp, wgt, slot, bias, out);
}